// Round 16
// baseline (588.315 us; speedup 1.0000x reference)
//
#include <hip/hip_runtime.h>
#include <hip/hip_fp16.h>
#include <stdint.h>

#define N_TOK 8192
#define DIMD 1024
#define NEXP 8
#define HDIM 2048
#define BM 256                  // M tile rows (raised from 128: +34% intensity)
#define BN 128
#define BKK 64
#define MAXT 72                 // sum ceil(c_e/256) <= 16384/256 + 8
#define MAXROWS (MAXT * 256)    // 18432 padded row slots
#define DUMPROW (2 * N_TOK)     // pair-buffer dump row for padding slots
#define CAP1 160                // per-XCD-lane affine capacity, gemm1 (j-slots)
#define CAP2 80                 // per-XCD-lane affine capacity, gemm2
#define G1 (8 * CAP1 + MAXT * 16)   // 1280 + 1152 = 2432
#define G2 (8 * CAP2 + MAXT * 8)    // 640 + 576 = 1216
#define TRB1 2048               // w1-transpose blocks (64x128 tiles) in prep
#define TW2 2048                // w2-transpose blocks (64x128 tiles) in gemm1 tail
#define SMEM1 49152             // gemm1 union: 48KB GEMM tiles >= 33KB transpose

typedef __attribute__((ext_vector_type(8))) short short8;
typedef __attribute__((ext_vector_type(4))) float f32x4;

__device__ __forceinline__ ushort f2bf(float f) {
    uint32_t u = __float_as_uint(f);
    u += 0x7fffu + ((u >> 16) & 1u);   // round-to-nearest-even
    return (ushort)(u >> 16);
}

// global -> LDS direct staging, 16B per lane. LDS dest is wave-uniform base.
__device__ __forceinline__ void gload_lds16(const void* gsrc, void* lds_dst) {
    __builtin_amdgcn_global_load_lds(
        (const __attribute__((address_space(1))) void*)(uintptr_t)(gsrc),
        (__attribute__((address_space(3))) void*)(uintptr_t)(lds_dst),
        16, 0, 0);
}

// Closed-form grid-slot -> (expert, tile, nb) map over 256-row tiles.
__device__ __forceinline__ bool slot_map(const int* __restrict__ counts, int s,
                                         int NB, int CAP,
                                         int* e_out, int* tm_out, int* nb_out) {
    int ec[8], es[8], tot = 0;
#pragma unroll
    for (int e = 0; e < 8; e++) { es[e] = tot; ec[e] = (counts[e] + 255) >> 8; tot += ec[e]; }
    int aff = 8 * CAP;
    if (s < aff) {
        int e = s & 7, j = s >> 3;
        int need = ec[e] * NB;
        int lim = need < CAP ? need : CAP;
        if (j >= lim) return false;
        *e_out = e; *tm_out = es[e] + j / NB; *nb_out = j % NB;
        return true;
    }
    int O = s - aff, acc = 0;
#pragma unroll
    for (int e = 0; e < 8; e++) {
        int over = ec[e] * NB - CAP; if (over < 0) over = 0;
        if (O < acc + over) {
            int j = CAP + (O - acc);
            *e_out = e; *tm_out = es[e] + j / NB; *nb_out = j % NB;
            return true;
        }
        acc += over;
    }
    return false;
}

// 64x128-tile transpose+convert: [R][C] f32 -> [C][R] bf16, NTH threads.
__device__ __forceinline__ void transpose_tile(const float* __restrict__ pin,
                                               ushort* __restrict__ pout,
                                               int R, int C, int rt, int ct,
                                               float (*t)[129], int tid, int NTH) {
    for (int q = tid; q < 2048; q += NTH) {
        int r = q >> 5, c4 = (q & 31) * 4;
        const float4 v = *(const float4*)(pin + (size_t)(rt * 64 + r) * C + ct * 128 + c4);
        t[r][c4] = v.x; t[r][c4 + 1] = v.y; t[r][c4 + 2] = v.z; t[r][c4 + 3] = v.w;
    }
    __syncthreads();
    for (int p = tid; p < 1024; p += NTH) {
        int c = p >> 3, rs = (p & 7) * 8;
        alignas(16) ushort tmp[8];
#pragma unroll
        for (int j = 0; j < 8; j++) tmp[j] = f2bf(t[rs + j][c]);
        *(short8*)(pout + (size_t)(ct * 128 + c) * R + rt * 64 + rs) = *(const short8*)tmp;
    }
}

// ---------------- prep: fused w1-transpose + gate + row-slot init -----------

__global__ void prep_kernel(const float* __restrict__ w1, ushort* __restrict__ w1t,
                            const float* __restrict__ x, const float* __restrict__ gw,
                            const float* __restrict__ gb, int* __restrict__ topi,
                            float* __restrict__ topw, int* __restrict__ counts,
                            float* __restrict__ probsum, ushort* __restrict__ xb,
                            int* __restrict__ row_token, float* __restrict__ row_weight) {
    __shared__ alignas(16) char smem[33024];
    int tid = threadIdx.x;
    if (blockIdx.x < TRB1) {
        int id = blockIdx.x;                     // w1: R=DIMD, C=HDIM; 16x16=256 tiles/e
        int e = id >> 8, tt = id & 255;
        int rt = tt >> 4, ct = tt & 15;
        transpose_tile(w1 + (size_t)e * DIMD * HDIM, w1t + (size_t)e * DIMD * HDIM,
                       DIMD, HDIM, rt, ct, (float(*)[129])smem, tid, 256);
        return;
    }
    // ---- gate path ----
    int gid = blockIdx.x - TRB1;                 // 0..2047
    float* ps = (float*)smem;
    int* cs = (int*)(smem + 64);
    if (gid < MAXROWS / 256) {                   // fused init_rows (72 blocks)
        int i = gid * 256 + tid;
        row_token[i] = DUMPROW; row_weight[i] = 0.f;
    }
    if (tid < NEXP) { ps[tid] = 0.f; cs[tid] = 0; }
    __syncthreads();
    int wid = tid >> 6, lane = tid & 63;
    int n = gid * 4 + wid;
    const float* xr = x + (size_t)n * DIMD;
    ushort* xbr = xb + (size_t)n * DIMD;
    float acc[NEXP];
#pragma unroll
    for (int e = 0; e < NEXP; e++) acc[e] = 0.f;
    for (int i = 0; i < DIMD / 64; i++) {
        int c = lane + i * 64;
        float xv = xr[c];
        xbr[c] = f2bf(xv);                       // fused conv_x
        const float4* g4 = (const float4*)(gw + (size_t)c * NEXP);
        float4 ga = g4[0], gbv = g4[1];
        acc[0] += xv * ga.x;  acc[1] += xv * ga.y;
        acc[2] += xv * ga.z;  acc[3] += xv * ga.w;
        acc[4] += xv * gbv.x; acc[5] += xv * gbv.y;
        acc[6] += xv * gbv.z; acc[7] += xv * gbv.w;
    }
#pragma unroll
    for (int e = 0; e < NEXP; e++) {
        float v = acc[e];
#pragma unroll
        for (int off = 32; off > 0; off >>= 1) v += __shfl_xor(v, off);
        acc[e] = v + gb[e];
    }
    float m = acc[0];
#pragma unroll
    for (int e = 1; e < NEXP; e++) m = fmaxf(m, acc[e]);
    float p[NEXP], s = 0.f;
#pragma unroll
    for (int e = 0; e < NEXP; e++) { p[e] = expf(acc[e] - m); s += p[e]; }
    int e1 = 0;
#pragma unroll
    for (int e = 1; e < NEXP; e++) if (p[e] > p[e1]) e1 = e;
    int e2 = (e1 == 0) ? 1 : 0;
#pragma unroll
    for (int e = 0; e < NEXP; e++) if (e != e1 && p[e] > p[e2]) e2 = e;
    float wa = p[e1] / (p[e1] + p[e2]);
    if (lane == 0) {
        topi[n * 2] = e1; topi[n * 2 + 1] = e2;
        topw[n * 2] = wa; topw[n * 2 + 1] = 1.f - wa;
        atomicAdd(&cs[e1], 1); atomicAdd(&cs[e2], 1);
        float inv = 1.f / s;
#pragma unroll
        for (int e = 0; e < NEXP; e++) atomicAdd(&ps[e], p[e] * inv);
    }
    __syncthreads();
    if (tid < NEXP) { atomicAdd(&probsum[tid], ps[tid]); atomicAdd(&counts[tid], cs[tid]); }
}

// ---------------- routing ----------------
// row_token stores the PAIR index p = token*2 + rank. Padding -> DUMPROW.

__global__ void scatter_kernel(const int* __restrict__ topi, const float* __restrict__ topw,
                               const int* __restrict__ counts, int* __restrict__ cursor,
                               int* __restrict__ row_token, float* __restrict__ row_weight) {
    __shared__ int lcnt[NEXP], lbase[NEXP];
    int t = blockIdx.x * 256 + threadIdx.x;       // pair index
    if (threadIdx.x < NEXP) lcnt[threadIdx.x] = 0;
    __syncthreads();
    int e = topi[t];
    int lpos = atomicAdd(&lcnt[e], 1);
    __syncthreads();
    if (threadIdx.x < NEXP) lbase[threadIdx.x] = atomicAdd(&cursor[threadIdx.x], lcnt[threadIdx.x]);
    __syncthreads();
    int pb = 0;
#pragma unroll
    for (int q = 0; q < NEXP; q++) {            // pbase[e] = sum_{q<e} ceil(c_q/256)*256
        int rounded = ((counts[q] + 255) >> 8) << 8;
        pb += (q < e) ? rounded : 0;
    }
    int pos = pb + lbase[e] + lpos;
    row_token[pos] = t;                         // pair index
    row_weight[pos] = topw[t];
}

// ---------------- grouped GEMMs ----------------
// 256x128 tile (87 FLOP/B staged, -25% L2 traffic/FLOP vs 128x128), BK=64,
// 8 waves (4M x 2N), mfma_f32_16x16x32_bf16. R9 single-48KB-buffer schedule:
//   ds_read ALL frags -> regs ; mid-sync ; stage next tile into SAME buffer ;
//   sched_barrier ; 32 reg-only MFMAs ; bottom-sync (vmcnt drain).
// Per-thread state identical to the proven 128^2 kernel (acc[4][4], 16
// ds_read, ~84 VGPR); 48KB LDS -> 3 blocks/CU (24 waves). launch_bounds
// (512,4) caps VGPR at 128 (does NOT force a squeeze - R11 spill lesson).
// LDS XOR-swizzle (byte ^= (row&7)<<4) on BOTH staging source and read.
// XCD-affine slot_map (s%8 == expert). gemm1 tail = w2 transpose.

__global__ __launch_bounds__(512, 4) void gemm1_kernel(
        const ushort* __restrict__ xb, const ushort* __restrict__ w1t,
        const float* __restrict__ b1, ushort* __restrict__ hbuf,
        const int* __restrict__ row_token, const int* __restrict__ counts,
        const float* __restrict__ w2, ushort* __restrict__ w2t) {
    __shared__ alignas(16) char smem[SMEM1];
    ushort* ldsA = (ushort*)smem;                // 32KB: [256][64] swizzled
    ushort* ldsB = (ushort*)(smem + 32768);      // 16KB: [128][64] swizzled
    int tid = threadIdx.x;
    if (blockIdx.x >= G1) {
        int id = blockIdx.x - G1;                // w2: R=HDIM, C=DIMD; 32x8=256 tiles/e
        int e = id >> 8, tt = id & 255;
        int rt = tt >> 3, ct = tt & 7;
        transpose_tile(w2 + (size_t)e * HDIM * DIMD, w2t + (size_t)e * HDIM * DIMD,
                       HDIM, DIMD, rt, ct, (float(*)[129])smem, tid, 512);
        return;
    }
    int e, tm, nb;
    if (!slot_map(counts, blockIdx.x, 16, CAP1, &e, &tm, &nb)) return;
    int nbase = nb * BN;
    int slotbase = tm * BM;
    int lane = tid & 63, wid = tid >> 6;
    int wr = wid >> 1, wc = wid & 1;             // 4M x 2N waves
    f32x4 acc[4][4];
#pragma unroll
    for (int i = 0; i < 4; i++)
#pragma unroll
        for (int j = 0; j < 4; j++) acc[i][j] = (f32x4){0.f, 0.f, 0.f, 0.f};
    // staging geometry: thread covers 4 A-chunks (64 rows each) + 2 B-chunks
    int srow = tid >> 3;                                   // 0..63 within chunk
    int scol = ((((tid & 7) * 16) ^ ((srow & 7) << 4)) >> 1);  // inv-swz (ushort)
    int tok[4];
#pragma unroll
    for (int i = 0; i < 4; i++)
        tok[i] = row_token[slotbase + i * 64 + srow] >> 1; // pair -> token
    const ushort* bmat = w1t + (size_t)e * HDIM * DIMD;
    const int NT = DIMD / BKK;

    // prologue: stage tile 0
#pragma unroll
    for (int i = 0; i < 4; i++)
        gload_lds16(xb + (size_t)tok[i] * DIMD + scol, ldsA + i * 4096 + tid * 8);
#pragma unroll
    for (int i = 0; i < 2; i++)
        gload_lds16(bmat + (size_t)(nbase + i * 64 + srow) * DIMD + scol,
                    ldsB + i * 4096 + tid * 8);
    __syncthreads();

    for (int kt = 0; kt < NT; kt++) {
        short8 af[4][2], bfv[4][2];
#pragma unroll
        for (int kk = 0; kk < 2; kk++) {
#pragma unroll
            for (int im = 0; im < 4; im++) {
                int row = wr * 64 + im * 16 + (lane & 15);
                int kbyte = kk * 64 + ((lane >> 4) * 16);
                af[im][kk] = *(const short8*)((const char*)ldsA +
                              row * 128 + (kbyte ^ ((row & 7) << 4)));
            }
#pragma unroll
            for (int in = 0; in < 4; in++) {
                int row = wc * 64 + in * 16 + (lane & 15);
                int kbyte = kk * 64 + ((lane >> 4) * 16);
                bfv[in][kk] = *(const short8*)((const char*)ldsB +
                               row * 128 + (kbyte ^ ((row & 7) << 4)));
            }
        }
        __syncthreads();                           // all reads done -> buffer reusable
        if (kt + 1 < NT) {
            int k0 = (kt + 1) * BKK;
#pragma unroll
            for (int i = 0; i < 4; i++)
                gload_lds16(xb + (size_t)tok[i] * DIMD + k0 + scol,
                            ldsA + i * 4096 + tid * 8);
#pragma unroll
            for (int i = 0; i < 2; i++)
                gload_lds16(bmat + (size_t)(nbase + i * 64 + srow) * DIMD + k0 + scol,
                            ldsB + i * 4096 + tid * 8);
        }
        __builtin_amdgcn_sched_barrier(0);         // pin load-issue before MFMAs
#pragma unroll
        for (int kk = 0; kk < 2; kk++)
#pragma unroll
            for (int im = 0; im < 4; im++)
#pragma unroll
                for (int in = 0; in < 4; in++)
                    acc[im][in] = __builtin_amdgcn_mfma_f32_16x16x32_bf16(
                        af[im][kk], bfv[in][kk], acc[im][in], 0, 0, 0);
        __syncthreads();                           // drains vmcnt(0): next tile ready
    }
    const float* b1e = b1 + (size_t)e * HDIM;
#pragma unroll
    for (int im = 0; im < 4; im++) {
#pragma unroll
        for (int in = 0; in < 4; in++) {
            int col = nbase + wc * 64 + in * 16 + (lane & 15);
            float bias = b1e[col];
#pragma unroll
            for (int r = 0; r < 4; r++) {
                int row = slotbase + wr * 64 + im * 16 + (lane >> 4) * 4 + r;
                float v = fmaxf(acc[im][in][r] + bias, 0.f);
                hbuf[(size_t)row * HDIM + col] = f2bf(v);
            }
        }
    }
}

__global__ __launch_bounds__(512, 4) void gemm2_kernel(
        const ushort* __restrict__ hbuf, const ushort* __restrict__ w2t,
        const float* __restrict__ b2, __half* __restrict__ pairbuf,
        const int* __restrict__ row_token, const float* __restrict__ row_weight,
        const int* __restrict__ counts) {
    int e, tm, nb;
    if (!slot_map(counts, blockIdx.x, 8, CAP2, &e, &tm, &nb)) return;
    int nbase = nb * BN;
    int slotbase = tm * BM;
    __shared__ alignas(16) ushort ldsA[BM * BKK];   // 32KB
    __shared__ alignas(16) ushort ldsB[BN * BKK];   // 16KB
    int tid = threadIdx.x, lane = tid & 63, wid = tid >> 6;
    int wr = wid >> 1, wc = wid & 1;
    f32x4 acc[4][4];
#pragma unroll
    for (int i = 0; i < 4; i++)
#pragma unroll
        for (int j = 0; j < 4; j++) acc[i][j] = (f32x4){0.f, 0.f, 0.f, 0.f};
    int srow = tid >> 3;
    int scol = ((((tid & 7) * 16) ^ ((srow & 7) << 4)) >> 1);
    const ushort* amat = hbuf + (size_t)slotbase * HDIM;
    const ushort* bmat = w2t + (size_t)e * DIMD * HDIM;
    const int NT = HDIM / BKK;

#pragma unroll
    for (int i = 0; i < 4; i++)
        gload_lds16(amat + (size_t)(i * 64 + srow) * HDIM + scol, ldsA + i * 4096 + tid * 8);
#pragma unroll
    for (int i = 0; i < 2; i++)
        gload_lds16(bmat + (size_t)(nbase + i * 64 + srow) * HDIM + scol,
                    ldsB + i * 4096 + tid * 8);
    __syncthreads();

    for (int kt = 0; kt < NT; kt++) {
        short8 af[4][2], bfv[4][2];
#pragma unroll
        for (int kk = 0; kk < 2; kk++) {
#pragma unroll
            for (int im = 0; im < 4; im++) {
                int row = wr * 64 + im * 16 + (lane & 15);
                int kbyte = kk * 64 + ((lane >> 4) * 16);
                af[im][kk] = *(const short8*)((const char*)ldsA +
                              row * 128 + (kbyte ^ ((row & 7) << 4)));
            }
#pragma unroll
            for (int in = 0; in < 4; in++) {
                int row = wc * 64 + in * 16 + (lane & 15);
                int kbyte = kk * 64 + ((lane >> 4) * 16);
                bfv[in][kk] = *(const short8*)((const char*)ldsB +
                               row * 128 + (kbyte ^ ((row & 7) << 4)));
            }
        }
        __syncthreads();
        if (kt + 1 < NT) {
            int k0 = (kt + 1) * BKK;
#pragma unroll
            for (int i = 0; i < 4; i++)
                gload_lds16(amat + (size_t)(i * 64 + srow) * HDIM + k0 + scol,
                            ldsA + i * 4096 + tid * 8);
#pragma unroll
            for (int i = 0; i < 2; i++)
                gload_lds16(bmat + (size_t)(nbase + i * 64 + srow) * HDIM + k0 + scol,
                            ldsB + i * 4096 + tid * 8);
        }
        __builtin_amdgcn_sched_barrier(0);
#pragma unroll
        for (int kk = 0; kk < 2; kk++)
#pragma unroll
            for (int im = 0; im < 4; im++)
#pragma unroll
                for (int in = 0; in < 4; in++)
                    acc[im][in] = __builtin_amdgcn_mfma_f32_16x16x32_bf16(
                        af[im][kk], bfv[in][kk], acc[im][in], 0, 0, 0);
        __syncthreads();
    }
    const float* b2e = b2 + (size_t)e * DIMD;
#pragma unroll
    for (int im = 0; im < 4; im++) {
#pragma unroll
        for (int r = 0; r < 4; r++) {
            int srw = slotbase + wr * 64 + im * 16 + (lane >> 4) * 4 + r;
            int pair = row_token[srw];
            float w = row_weight[srw];
            __half* prow = pairbuf + (size_t)pair * DIMD;
#pragma unroll
            for (int in = 0; in < 4; in++) {
                int col = nbase + wc * 64 + in * 16 + (lane & 15);
                float v = acc[im][in][r] + b2e[col];
                prow[col] = __float2half(w * v);     // plain store, no atomic
            }
        }
    }
}

// out[t][d] = pairbuf[2t][d] + pairbuf[2t+1][d]  + fused loss finalize.
__global__ void combine_kernel(const __half* __restrict__ pairbuf, float* __restrict__ outp,
                               const float* __restrict__ probsum, const int* __restrict__ counts) {
    int i = blockIdx.x * blockDim.x + threadIdx.x;
    int o = i * 8;
    int t = o >> 10, d = o & 1023;
    const __half* p0 = pairbuf + ((size_t)(t * 2) << 10) + d;
    const __half* p1 = p0 + DIMD;
    short8 h0 = *(const short8*)p0;
    short8 h1 = *(const short8*)p1;
    float4 r0, r1;
#pragma unroll
    for (int j = 0; j < 4; j++) {
        ((float*)&r0)[j] = __half2float(__ushort_as_half((ushort)h0[j])) +
                           __half2float(__ushort_as_half((ushort)h1[j]));
        ((float*)&r1)[j] = __half2float(__ushort_as_half((ushort)h0[j + 4])) +
                           __half2float(__ushort_as_half((ushort)h1[j + 4]));
    }
    float4* dst = (float4*)(outp + o);
    dst[0] = r0; dst[1] = r1;
    if (i == 0) {
        float l = 0.f;
#pragma unroll
        for (int e = 0; e < NEXP; e++) l += probsum[e] * (float)counts[e];
        outp[(size_t)N_TOK * DIMD] = l / ((float)N_TOK * (float)N_TOK);
    }
}

// ---------------- launch ----------------

extern "C" void kernel_launch(void* const* d_in, const int* in_sizes, int n_in,
                              void* d_out, int out_size, void* d_ws, size_t ws_size,
                              hipStream_t stream) {
    const float* x      = (const float*)d_in[0];
    const float* gate_w = (const float*)d_in[1];
    const float* gate_b = (const float*)d_in[2];
    const float* w1     = (const float*)d_in[3];
    const float* b1     = (const float*)d_in[4];
    const float* w2     = (const float*)d_in[5];
    const float* b2     = (const float*)d_in[6];
    float* outp = (float*)d_out;

    char* ws = (char*)d_ws;
    ushort* xb   = (ushort*)(ws);                 // 16.8 MB   [dead after gemm1]
    ushort* w1t  = (ushort*)(ws + 16777216);      // 33.6 MB   [dead after gemm1]
    ushort* w2t  = (ushort*)(ws + 50331648);      // 33.6 MB  [E][D][H] bf16
    ushort* hbuf = (ushort*)(ws + 83886080);      // 75.5 MB  [MAXROWS][H] bf16
    __half* pairbuf = (__half*)(ws);              // 33.6 MB  [2N+1][D] f16 (overlays xb/w1t)
    char* ctrl   = ws + 159383552;
    int*   counts     = (int*)(ctrl + 0);
    int*   cursor     = (int*)(ctrl + 32);
    float* probsum    = (float*)(ctrl + 64);
    int*   topi       = (int*)(ctrl + 2048);
    float* topw       = (float*)(ctrl + 2048 + 65536);
    int*   row_token  = (int*)(ctrl + 2048 + 131072);
    float* row_weight = (float*)(ctrl + 2048 + 131072 + 73728);

    hipMemsetAsync(ctrl, 0, 128, stream);

    prep_kernel<<<TRB1 + N_TOK / 4, 256, 0, stream>>>(w1, w1t, x, gate_w, gate_b,
                                                      topi, topw, counts, probsum, xb,
                                                      row_token, row_weight);
    scatter_kernel<<<(N_TOK * 2) / 256, 256, 0, stream>>>(topi, topw, counts, cursor,
                                                          row_token, row_weight);
    gemm1_kernel<<<G1 + TW2, 512, 0, stream>>>(xb, w1t, b1, hbuf, row_token, counts,
                                               w2, w2t);
    gemm2_kernel<<<G2, 512, 0, stream>>>(hbuf, w2t, b2, pairbuf, row_token, row_weight, counts);
    combine_kernel<<<(N_TOK * DIMD / 8) / 256, 256, 0, stream>>>(pairbuf, outp,
                                                                 probsum, counts);
}

// Round 17
// 349.771 us; speedup vs baseline: 1.6820x; 1.6820x over previous
//
#include <hip/hip_runtime.h>
#include <hip/hip_fp16.h>
#include <stdint.h>

#define N_TOK 8192
#define DIMD 1024
#define NEXP 8
#define HDIM 2048
#define BM 256                  // M tile rows (raised from 128: +34% intensity)
#define BN 128
#define BKK 64
#define MAXT 72                 // sum ceil(c_e/256) <= 16384/256 + 8
#define MAXROWS (MAXT * 256)    // 18432 padded row slots
#define DUMPROW (2 * N_TOK)     // pair-buffer dump row for padding slots
#define CAP1 160                // per-XCD-lane affine capacity, gemm1 (j-slots)
#define CAP2 80                 // per-XCD-lane affine capacity, gemm2
#define G1 (8 * CAP1 + MAXT * 16)   // 1280 + 1152 = 2432
#define G2 (8 * CAP2 + MAXT * 8)    // 640 + 576 = 1216
#define TRB1 2048               // w1-transpose blocks (64x128 tiles) in prep
#define TW2 2048                // w2-transpose blocks (64x128 tiles) in gemm1 tail
#define SMEM1 49152             // gemm1 union: 48KB GEMM tiles >= 33KB transpose

typedef __attribute__((ext_vector_type(8))) short short8;
typedef __attribute__((ext_vector_type(4))) float f32x4;

__device__ __forceinline__ ushort f2bf(float f) {
    uint32_t u = __float_as_uint(f);
    u += 0x7fffu + ((u >> 16) & 1u);   // round-to-nearest-even
    return (ushort)(u >> 16);
}

// global -> LDS direct staging, 16B per lane. LDS dest is wave-uniform base.
__device__ __forceinline__ void gload_lds16(const void* gsrc, void* lds_dst) {
    __builtin_amdgcn_global_load_lds(
        (const __attribute__((address_space(1))) void*)(uintptr_t)(gsrc),
        (__attribute__((address_space(3))) void*)(uintptr_t)(lds_dst),
        16, 0, 0);
}

// Closed-form grid-slot -> (expert, tile, nb) map over 256-row tiles.
__device__ __forceinline__ bool slot_map(const int* __restrict__ counts, int s,
                                         int NB, int CAP,
                                         int* e_out, int* tm_out, int* nb_out) {
    int ec[8], es[8], tot = 0;
#pragma unroll
    for (int e = 0; e < 8; e++) { es[e] = tot; ec[e] = (counts[e] + 255) >> 8; tot += ec[e]; }
    int aff = 8 * CAP;
    if (s < aff) {
        int e = s & 7, j = s >> 3;
        int need = ec[e] * NB;
        int lim = need < CAP ? need : CAP;
        if (j >= lim) return false;
        *e_out = e; *tm_out = es[e] + j / NB; *nb_out = j % NB;
        return true;
    }
    int O = s - aff, acc = 0;
#pragma unroll
    for (int e = 0; e < 8; e++) {
        int over = ec[e] * NB - CAP; if (over < 0) over = 0;
        if (O < acc + over) {
            int j = CAP + (O - acc);
            *e_out = e; *tm_out = es[e] + j / NB; *nb_out = j % NB;
            return true;
        }
        acc += over;
    }
    return false;
}

// 64x128-tile transpose+convert: [R][C] f32 -> [C][R] bf16, NTH threads.
__device__ __forceinline__ void transpose_tile(const float* __restrict__ pin,
                                               ushort* __restrict__ pout,
                                               int R, int C, int rt, int ct,
                                               float (*t)[129], int tid, int NTH) {
    for (int q = tid; q < 2048; q += NTH) {
        int r = q >> 5, c4 = (q & 31) * 4;
        const float4 v = *(const float4*)(pin + (size_t)(rt * 64 + r) * C + ct * 128 + c4);
        t[r][c4] = v.x; t[r][c4 + 1] = v.y; t[r][c4 + 2] = v.z; t[r][c4 + 3] = v.w;
    }
    __syncthreads();
    for (int p = tid; p < 1024; p += NTH) {
        int c = p >> 3, rs = (p & 7) * 8;
        alignas(16) ushort tmp[8];
#pragma unroll
        for (int j = 0; j < 8; j++) tmp[j] = f2bf(t[rs + j][c]);
        *(short8*)(pout + (size_t)(ct * 128 + c) * R + rt * 64 + rs) = *(const short8*)tmp;
    }
}

// ---------------- prep: fused w1-transpose + gate + row-slot init -----------

__global__ void prep_kernel(const float* __restrict__ w1, ushort* __restrict__ w1t,
                            const float* __restrict__ x, const float* __restrict__ gw,
                            const float* __restrict__ gb, int* __restrict__ topi,
                            float* __restrict__ topw, int* __restrict__ counts,
                            float* __restrict__ probsum, ushort* __restrict__ xb,
                            int* __restrict__ row_token, float* __restrict__ row_weight) {
    __shared__ alignas(16) char smem[33024];
    int tid = threadIdx.x;
    if (blockIdx.x < TRB1) {
        int id = blockIdx.x;                     // w1: R=DIMD, C=HDIM; 16x16=256 tiles/e
        int e = id >> 8, tt = id & 255;
        int rt = tt >> 4, ct = tt & 15;
        transpose_tile(w1 + (size_t)e * DIMD * HDIM, w1t + (size_t)e * DIMD * HDIM,
                       DIMD, HDIM, rt, ct, (float(*)[129])smem, tid, 256);
        return;
    }
    // ---- gate path ----
    int gid = blockIdx.x - TRB1;                 // 0..2047
    float* ps = (float*)smem;
    int* cs = (int*)(smem + 64);
    if (gid < MAXROWS / 256) {                   // fused init_rows (72 blocks)
        int i = gid * 256 + tid;
        row_token[i] = DUMPROW; row_weight[i] = 0.f;
    }
    if (tid < NEXP) { ps[tid] = 0.f; cs[tid] = 0; }
    __syncthreads();
    int wid = tid >> 6, lane = tid & 63;
    int n = gid * 4 + wid;
    const float* xr = x + (size_t)n * DIMD;
    ushort* xbr = xb + (size_t)n * DIMD;
    float acc[NEXP];
#pragma unroll
    for (int e = 0; e < NEXP; e++) acc[e] = 0.f;
    for (int i = 0; i < DIMD / 64; i++) {
        int c = lane + i * 64;
        float xv = xr[c];
        xbr[c] = f2bf(xv);                       // fused conv_x
        const float4* g4 = (const float4*)(gw + (size_t)c * NEXP);
        float4 ga = g4[0], gbv = g4[1];
        acc[0] += xv * ga.x;  acc[1] += xv * ga.y;
        acc[2] += xv * ga.z;  acc[3] += xv * ga.w;
        acc[4] += xv * gbv.x; acc[5] += xv * gbv.y;
        acc[6] += xv * gbv.z; acc[7] += xv * gbv.w;
    }
#pragma unroll
    for (int e = 0; e < NEXP; e++) {
        float v = acc[e];
#pragma unroll
        for (int off = 32; off > 0; off >>= 1) v += __shfl_xor(v, off);
        acc[e] = v + gb[e];
    }
    float m = acc[0];
#pragma unroll
    for (int e = 1; e < NEXP; e++) m = fmaxf(m, acc[e]);
    float p[NEXP], s = 0.f;
#pragma unroll
    for (int e = 0; e < NEXP; e++) { p[e] = expf(acc[e] - m); s += p[e]; }
    int e1 = 0;
#pragma unroll
    for (int e = 1; e < NEXP; e++) if (p[e] > p[e1]) e1 = e;
    int e2 = (e1 == 0) ? 1 : 0;
#pragma unroll
    for (int e = 0; e < NEXP; e++) if (e != e1 && p[e] > p[e2]) e2 = e;
    float wa = p[e1] / (p[e1] + p[e2]);
    if (lane == 0) {
        topi[n * 2] = e1; topi[n * 2 + 1] = e2;
        topw[n * 2] = wa; topw[n * 2 + 1] = 1.f - wa;
        atomicAdd(&cs[e1], 1); atomicAdd(&cs[e2], 1);
        float inv = 1.f / s;
#pragma unroll
        for (int e = 0; e < NEXP; e++) atomicAdd(&ps[e], p[e] * inv);
    }
    __syncthreads();
    if (tid < NEXP) { atomicAdd(&probsum[tid], ps[tid]); atomicAdd(&counts[tid], cs[tid]); }
}

// ---------------- routing ----------------
// row_token stores the PAIR index p = token*2 + rank. Padding -> DUMPROW.

__global__ void scatter_kernel(const int* __restrict__ topi, const float* __restrict__ topw,
                               const int* __restrict__ counts, int* __restrict__ cursor,
                               int* __restrict__ row_token, float* __restrict__ row_weight) {
    __shared__ int lcnt[NEXP], lbase[NEXP];
    int t = blockIdx.x * 256 + threadIdx.x;       // pair index
    if (threadIdx.x < NEXP) lcnt[threadIdx.x] = 0;
    __syncthreads();
    int e = topi[t];
    int lpos = atomicAdd(&lcnt[e], 1);
    __syncthreads();
    if (threadIdx.x < NEXP) lbase[threadIdx.x] = atomicAdd(&cursor[threadIdx.x], lcnt[threadIdx.x]);
    __syncthreads();
    int pb = 0;
#pragma unroll
    for (int q = 0; q < NEXP; q++) {            // pbase[e] = sum_{q<e} ceil(c_q/256)*256
        int rounded = ((counts[q] + 255) >> 8) << 8;
        pb += (q < e) ? rounded : 0;
    }
    int pos = pb + lbase[e] + lpos;
    row_token[pos] = t;                         // pair index
    row_weight[pos] = topw[t];
}

// ---------------- grouped GEMMs ----------------
// 256x128 tile (87 FLOP/B staged, -25% L2 traffic/FLOP vs 128x128), BK=64,
// 8 waves (4M x 2N), mfma_f32_16x16x32_bf16. R9 single-48KB-buffer schedule:
//   ds_read ALL frags -> regs ; mid-sync ; stage next tile into SAME buffer ;
//   sched_barrier ; 32 reg-only MFMAs ; bottom-sync (vmcnt drain).
// __launch_bounds__(512) ONLY - no min-occupancy arg. R11+R16 lesson: any
// occupancy floor that pushes the allocator below the ~84-VGPR working set
// causes accumulator spill (VGPR 64, WRITE_SIZE 34->444MB, 4x slower).
// Natural allocation ~84 VGPR -> LDS-limited 3 blocks/CU (48KB).
// LDS XOR-swizzle (byte ^= (row&7)<<4) on BOTH staging source and read.
// XCD-affine slot_map (s%8 == expert). gemm1 tail = w2 transpose.

__global__ __launch_bounds__(512) void gemm1_kernel(
        const ushort* __restrict__ xb, const ushort* __restrict__ w1t,
        const float* __restrict__ b1, ushort* __restrict__ hbuf,
        const int* __restrict__ row_token, const int* __restrict__ counts,
        const float* __restrict__ w2, ushort* __restrict__ w2t) {
    __shared__ alignas(16) char smem[SMEM1];
    ushort* ldsA = (ushort*)smem;                // 32KB: [256][64] swizzled
    ushort* ldsB = (ushort*)(smem + 32768);      // 16KB: [128][64] swizzled
    int tid = threadIdx.x;
    if (blockIdx.x >= G1) {
        int id = blockIdx.x - G1;                // w2: R=HDIM, C=DIMD; 32x8=256 tiles/e
        int e = id >> 8, tt = id & 255;
        int rt = tt >> 3, ct = tt & 7;
        transpose_tile(w2 + (size_t)e * HDIM * DIMD, w2t + (size_t)e * HDIM * DIMD,
                       HDIM, DIMD, rt, ct, (float(*)[129])smem, tid, 512);
        return;
    }
    int e, tm, nb;
    if (!slot_map(counts, blockIdx.x, 16, CAP1, &e, &tm, &nb)) return;
    int nbase = nb * BN;
    int slotbase = tm * BM;
    int lane = tid & 63, wid = tid >> 6;
    int wr = wid >> 1, wc = wid & 1;             // 4M x 2N waves
    f32x4 acc[4][4];
#pragma unroll
    for (int i = 0; i < 4; i++)
#pragma unroll
        for (int j = 0; j < 4; j++) acc[i][j] = (f32x4){0.f, 0.f, 0.f, 0.f};
    // staging geometry: thread covers 4 A-chunks (64 rows each) + 2 B-chunks
    int srow = tid >> 3;                                   // 0..63 within chunk
    int scol = ((((tid & 7) * 16) ^ ((srow & 7) << 4)) >> 1);  // inv-swz (ushort)
    int tok[4];
#pragma unroll
    for (int i = 0; i < 4; i++)
        tok[i] = row_token[slotbase + i * 64 + srow] >> 1; // pair -> token
    const ushort* bmat = w1t + (size_t)e * HDIM * DIMD;
    const int NT = DIMD / BKK;

    // prologue: stage tile 0
#pragma unroll
    for (int i = 0; i < 4; i++)
        gload_lds16(xb + (size_t)tok[i] * DIMD + scol, ldsA + i * 4096 + tid * 8);
#pragma unroll
    for (int i = 0; i < 2; i++)
        gload_lds16(bmat + (size_t)(nbase + i * 64 + srow) * DIMD + scol,
                    ldsB + i * 4096 + tid * 8);
    __syncthreads();

    for (int kt = 0; kt < NT; kt++) {
        short8 af[4][2], bfv[4][2];
#pragma unroll
        for (int kk = 0; kk < 2; kk++) {
#pragma unroll
            for (int im = 0; im < 4; im++) {
                int row = wr * 64 + im * 16 + (lane & 15);
                int kbyte = kk * 64 + ((lane >> 4) * 16);
                af[im][kk] = *(const short8*)((const char*)ldsA +
                              row * 128 + (kbyte ^ ((row & 7) << 4)));
            }
#pragma unroll
            for (int in = 0; in < 4; in++) {
                int row = wc * 64 + in * 16 + (lane & 15);
                int kbyte = kk * 64 + ((lane >> 4) * 16);
                bfv[in][kk] = *(const short8*)((const char*)ldsB +
                               row * 128 + (kbyte ^ ((row & 7) << 4)));
            }
        }
        __syncthreads();                           // all reads done -> buffer reusable
        if (kt + 1 < NT) {
            int k0 = (kt + 1) * BKK;
#pragma unroll
            for (int i = 0; i < 4; i++)
                gload_lds16(xb + (size_t)tok[i] * DIMD + k0 + scol,
                            ldsA + i * 4096 + tid * 8);
#pragma unroll
            for (int i = 0; i < 2; i++)
                gload_lds16(bmat + (size_t)(nbase + i * 64 + srow) * DIMD + k0 + scol,
                            ldsB + i * 4096 + tid * 8);
        }
        __builtin_amdgcn_sched_barrier(0);         // pin load-issue before MFMAs
#pragma unroll
        for (int kk = 0; kk < 2; kk++)
#pragma unroll
            for (int im = 0; im < 4; im++)
#pragma unroll
                for (int in = 0; in < 4; in++)
                    acc[im][in] = __builtin_amdgcn_mfma_f32_16x16x32_bf16(
                        af[im][kk], bfv[in][kk], acc[im][in], 0, 0, 0);
        __syncthreads();                           // drains vmcnt(0): next tile ready
    }
    const float* b1e = b1 + (size_t)e * HDIM;
#pragma unroll
    for (int im = 0; im < 4; im++) {
#pragma unroll
        for (int in = 0; in < 4; in++) {
            int col = nbase + wc * 64 + in * 16 + (lane & 15);
            float bias = b1e[col];
#pragma unroll
            for (int r = 0; r < 4; r++) {
                int row = slotbase + wr * 64 + im * 16 + (lane >> 4) * 4 + r;
                float v = fmaxf(acc[im][in][r] + bias, 0.f);
                hbuf[(size_t)row * HDIM + col] = f2bf(v);
            }
        }
    }
}

__global__ __launch_bounds__(512) void gemm2_kernel(
        const ushort* __restrict__ hbuf, const ushort* __restrict__ w2t,
        const float* __restrict__ b2, __half* __restrict__ pairbuf,
        const int* __restrict__ row_token, const float* __restrict__ row_weight,
        const int* __restrict__ counts) {
    int e, tm, nb;
    if (!slot_map(counts, blockIdx.x, 8, CAP2, &e, &tm, &nb)) return;
    int nbase = nb * BN;
    int slotbase = tm * BM;
    __shared__ alignas(16) ushort ldsA[BM * BKK];   // 32KB
    __shared__ alignas(16) ushort ldsB[BN * BKK];   // 16KB
    int tid = threadIdx.x, lane = tid & 63, wid = tid >> 6;
    int wr = wid >> 1, wc = wid & 1;
    f32x4 acc[4][4];
#pragma unroll
    for (int i = 0; i < 4; i++)
#pragma unroll
        for (int j = 0; j < 4; j++) acc[i][j] = (f32x4){0.f, 0.f, 0.f, 0.f};
    int srow = tid >> 3;
    int scol = ((((tid & 7) * 16) ^ ((srow & 7) << 4)) >> 1);
    const ushort* amat = hbuf + (size_t)slotbase * HDIM;
    const ushort* bmat = w2t + (size_t)e * DIMD * HDIM;
    const int NT = HDIM / BKK;

#pragma unroll
    for (int i = 0; i < 4; i++)
        gload_lds16(amat + (size_t)(i * 64 + srow) * HDIM + scol, ldsA + i * 4096 + tid * 8);
#pragma unroll
    for (int i = 0; i < 2; i++)
        gload_lds16(bmat + (size_t)(nbase + i * 64 + srow) * HDIM + scol,
                    ldsB + i * 4096 + tid * 8);
    __syncthreads();

    for (int kt = 0; kt < NT; kt++) {
        short8 af[4][2], bfv[4][2];
#pragma unroll
        for (int kk = 0; kk < 2; kk++) {
#pragma unroll
            for (int im = 0; im < 4; im++) {
                int row = wr * 64 + im * 16 + (lane & 15);
                int kbyte = kk * 64 + ((lane >> 4) * 16);
                af[im][kk] = *(const short8*)((const char*)ldsA +
                              row * 128 + (kbyte ^ ((row & 7) << 4)));
            }
#pragma unroll
            for (int in = 0; in < 4; in++) {
                int row = wc * 64 + in * 16 + (lane & 15);
                int kbyte = kk * 64 + ((lane >> 4) * 16);
                bfv[in][kk] = *(const short8*)((const char*)ldsB +
                               row * 128 + (kbyte ^ ((row & 7) << 4)));
            }
        }
        __syncthreads();
        if (kt + 1 < NT) {
            int k0 = (kt + 1) * BKK;
#pragma unroll
            for (int i = 0; i < 4; i++)
                gload_lds16(amat + (size_t)(i * 64 + srow) * HDIM + k0 + scol,
                            ldsA + i * 4096 + tid * 8);
#pragma unroll
            for (int i = 0; i < 2; i++)
                gload_lds16(bmat + (size_t)(nbase + i * 64 + srow) * HDIM + k0 + scol,
                            ldsB + i * 4096 + tid * 8);
        }
        __builtin_amdgcn_sched_barrier(0);
#pragma unroll
        for (int kk = 0; kk < 2; kk++)
#pragma unroll
            for (int im = 0; im < 4; im++)
#pragma unroll
                for (int in = 0; in < 4; in++)
                    acc[im][in] = __builtin_amdgcn_mfma_f32_16x16x32_bf16(
                        af[im][kk], bfv[in][kk], acc[im][in], 0, 0, 0);
        __syncthreads();
    }
    const float* b2e = b2 + (size_t)e * DIMD;
#pragma unroll
    for (int im = 0; im < 4; im++) {
#pragma unroll
        for (int r = 0; r < 4; r++) {
            int srw = slotbase + wr * 64 + im * 16 + (lane >> 4) * 4 + r;
            int pair = row_token[srw];
            float w = row_weight[srw];
            __half* prow = pairbuf + (size_t)pair * DIMD;
#pragma unroll
            for (int in = 0; in < 4; in++) {
                int col = nbase + wc * 64 + in * 16 + (lane & 15);
                float v = acc[im][in][r] + b2e[col];
                prow[col] = __float2half(w * v);     // plain store, no atomic
            }
        }
    }
}

// out[t][d] = pairbuf[2t][d] + pairbuf[2t+1][d]  + fused loss finalize.
__global__ void combine_kernel(const __half* __restrict__ pairbuf, float* __restrict__ outp,
                               const float* __restrict__ probsum, const int* __restrict__ counts) {
    int i = blockIdx.x * blockDim.x + threadIdx.x;
    int o = i * 8;
    int t = o >> 10, d = o & 1023;
    const __half* p0 = pairbuf + ((size_t)(t * 2) << 10) + d;
    const __half* p1 = p0 + DIMD;
    short8 h0 = *(const short8*)p0;
    short8 h1 = *(const short8*)p1;
    float4 r0, r1;
#pragma unroll
    for (int j = 0; j < 4; j++) {
        ((float*)&r0)[j] = __half2float(__ushort_as_half((ushort)h0[j])) +
                           __half2float(__ushort_as_half((ushort)h1[j]));
        ((float*)&r1)[j] = __half2float(__ushort_as_half((ushort)h0[j + 4])) +
                           __half2float(__ushort_as_half((ushort)h1[j + 4]));
    }
    float4* dst = (float4*)(outp + o);
    dst[0] = r0; dst[1] = r1;
    if (i == 0) {
        float l = 0.f;
#pragma unroll
        for (int e = 0; e < NEXP; e++) l += probsum[e] * (float)counts[e];
        outp[(size_t)N_TOK * DIMD] = l / ((float)N_TOK * (float)N_TOK);
    }
}

// ---------------- launch ----------------

extern "C" void kernel_launch(void* const* d_in, const int* in_sizes, int n_in,
                              void* d_out, int out_size, void* d_ws, size_t ws_size,
                              hipStream_t stream) {
    const float* x      = (const float*)d_in[0];
    const float* gate_w = (const float*)d_in[1];
    const float* gate_b = (const float*)d_in[2];
    const float* w1     = (const float*)d_in[3];
    const float* b1     = (const float*)d_in[4];
    const float* w2     = (const float*)d_in[5];
    const float* b2     = (const float*)d_in[6];
    float* outp = (float*)d_out;

    char* ws = (char*)d_ws;
    ushort* xb   = (ushort*)(ws);                 // 16.8 MB   [dead after gemm1]
    ushort* w1t  = (ushort*)(ws + 16777216);      // 33.6 MB   [dead after gemm1]
    ushort* w2t  = (ushort*)(ws + 50331648);      // 33.6 MB  [E][D][H] bf16
    ushort* hbuf = (ushort*)(ws + 83886080);      // 75.5 MB  [MAXROWS][H] bf16
    __half* pairbuf = (__half*)(ws);              // 33.6 MB  [2N+1][D] f16 (overlays xb/w1t)
    char* ctrl   = ws + 159383552;
    int*   counts     = (int*)(ctrl + 0);
    int*   cursor     = (int*)(ctrl + 32);
    float* probsum    = (float*)(ctrl + 64);
    int*   topi       = (int*)(ctrl + 2048);
    float* topw       = (float*)(ctrl + 2048 + 65536);
    int*   row_token  = (int*)(ctrl + 2048 + 131072);
    float* row_weight = (float*)(ctrl + 2048 + 131072 + 73728);

    hipMemsetAsync(ctrl, 0, 128, stream);

    prep_kernel<<<TRB1 + N_TOK / 4, 256, 0, stream>>>(w1, w1t, x, gate_w, gate_b,
                                                      topi, topw, counts, probsum, xb,
                                                      row_token, row_weight);
    scatter_kernel<<<(N_TOK * 2) / 256, 256, 0, stream>>>(topi, topw, counts, cursor,
                                                          row_token, row_weight);
    gemm1_kernel<<<G1 + TW2, 512, 0, stream>>>(xb, w1t, b1, hbuf, row_token, counts,
                                               w2, w2t);
    gemm2_kernel<<<G2, 512, 0, stream>>>(hbuf, w2t, b2, pairbuf, row_token, row_weight, counts);
    combine_kernel<<<(N_TOK * DIMD / 8) / 256, 256, 0, stream>>>(pairbuf, outp,
                                                                 probsum, counts);
}

// Round 18
// 230.159 us; speedup vs baseline: 2.5561x; 1.5197x over previous
//
#include <hip/hip_runtime.h>
#include <hip/hip_fp16.h>
#include <stdint.h>

#define N_TOK 8192
#define DIMD 1024
#define NEXP 8
#define HDIM 2048
#define BM 128
#define BN 128
#define BKK 64
#define MAXTILES 136            // sum ceil(c_e/128) <= 16384/128 + 8
#define MAXROWS (MAXTILES * BM) // 17408 padded row slots
#define DUMPROW (2 * N_TOK)     // pair-buffer dump row for padding slots
#define CAP1 320                // per-XCD-lane affine capacity, gemm1 (j-slots)
#define CAP2 160                // per-XCD-lane affine capacity, gemm2
#define G1 (8 * CAP1 + MAXTILES * 16)   // 2560 + 2176 = 4736
#define G2 (8 * CAP2 + MAXTILES * 8)    // 1280 + 1088 = 2368
#define TRB1 2048               // w1-transpose blocks (64x128 tiles) in prep
#define TW2 2048                // w2-transpose blocks (64x128 tiles) in gemm1 tail
#define SMEM_BYTES 33024        // max(32KB GEMM tiles, 64*129*4 transpose tile)

typedef __attribute__((ext_vector_type(8))) short short8;
typedef __attribute__((ext_vector_type(4))) float f32x4;

__device__ __forceinline__ ushort f2bf(float f) {
    uint32_t u = __float_as_uint(f);
    u += 0x7fffu + ((u >> 16) & 1u);   // round-to-nearest-even
    return (ushort)(u >> 16);
}

// global -> LDS direct staging, 16B per lane. LDS dest is wave-uniform base.
__device__ __forceinline__ void gload_lds16(const void* gsrc, void* lds_dst) {
    __builtin_amdgcn_global_load_lds(
        (const __attribute__((address_space(1))) void*)(uintptr_t)(gsrc),
        (__attribute__((address_space(3))) void*)(uintptr_t)(lds_dst),
        16, 0, 0);
}

// Closed-form grid-slot -> (expert, tile, nb) map. Affine region keeps expert e
// on XCD lane s%8==e with same-tile blocks consecutive per lane; overflow
// region (s >= 8*CAP) covers arbitrary imbalance deterministically.
__device__ __forceinline__ bool slot_map(const int* __restrict__ counts, int s,
                                         int NB, int CAP,
                                         int* e_out, int* tm_out, int* nb_out) {
    int ec[8], es[8], tot = 0;
#pragma unroll
    for (int e = 0; e < 8; e++) { es[e] = tot; ec[e] = (counts[e] + 127) >> 7; tot += ec[e]; }
    int aff = 8 * CAP;
    if (s < aff) {
        int e = s & 7, j = s >> 3;
        int need = ec[e] * NB;
        int lim = need < CAP ? need : CAP;
        if (j >= lim) return false;
        *e_out = e; *tm_out = es[e] + j / NB; *nb_out = j % NB;
        return true;
    }
    int O = s - aff, acc = 0;
#pragma unroll
    for (int e = 0; e < 8; e++) {
        int over = ec[e] * NB - CAP; if (over < 0) over = 0;
        if (O < acc + over) {
            int j = CAP + (O - acc);
            *e_out = e; *tm_out = es[e] + j / NB; *nb_out = j % NB;
            return true;
        }
        acc += over;
    }
    return false;
}

// 64x128-tile transpose+convert: [R][C] f32 -> [C][R] bf16 for one tile.
__device__ __forceinline__ void transpose_tile(const float* __restrict__ pin,
                                               ushort* __restrict__ pout,
                                               int R, int C, int rt, int ct,
                                               float (*t)[129], int tid) {
#pragma unroll
    for (int k = 0; k < 8; k++) {
        int q = tid + k * 256;
        int r = q >> 5, c4 = (q & 31) * 4;
        const float4 v = *(const float4*)(pin + (size_t)(rt * 64 + r) * C + ct * 128 + c4);
        t[r][c4] = v.x; t[r][c4 + 1] = v.y; t[r][c4 + 2] = v.z; t[r][c4 + 3] = v.w;
    }
    __syncthreads();
#pragma unroll
    for (int k = 0; k < 4; k++) {
        int p = tid + k * 256;
        int c = p >> 3, rs = (p & 7) * 8;
        alignas(16) ushort tmp[8];
#pragma unroll
        for (int j = 0; j < 8; j++) tmp[j] = f2bf(t[rs + j][c]);
        *(short8*)(pout + (size_t)(ct * 128 + c) * R + rt * 64 + rs) = *(const short8*)tmp;
    }
}

// ---------------- prep: fused w1-transpose + gate + row-slot init -----------

__global__ void prep_kernel(const float* __restrict__ w1, ushort* __restrict__ w1t,
                            const float* __restrict__ x, const float* __restrict__ gw,
                            const float* __restrict__ gb, int* __restrict__ topi,
                            float* __restrict__ topw, int* __restrict__ counts,
                            float* __restrict__ probsum, ushort* __restrict__ xb,
                            int* __restrict__ row_token, float* __restrict__ row_weight) {
    __shared__ alignas(16) char smem[SMEM_BYTES];
    int tid = threadIdx.x;
    if (blockIdx.x < TRB1) {
        int id = blockIdx.x;                     // w1: R=DIMD, C=HDIM; 16x16=256 tiles/e
        int e = id >> 8, tt = id & 255;
        int rt = tt >> 4, ct = tt & 15;
        transpose_tile(w1 + (size_t)e * DIMD * HDIM, w1t + (size_t)e * DIMD * HDIM,
                       DIMD, HDIM, rt, ct, (float(*)[129])smem, tid);
        return;
    }
    // ---- gate path ----
    int gid = blockIdx.x - TRB1;                 // 0..2047
    float* ps = (float*)smem;
    int* cs = (int*)(smem + 64);
    if (gid < MAXROWS / 256) {                   // fused init_rows
        int i = gid * 256 + tid;
        row_token[i] = DUMPROW; row_weight[i] = 0.f;
    }
    if (tid < NEXP) { ps[tid] = 0.f; cs[tid] = 0; }
    __syncthreads();
    int wid = tid >> 6, lane = tid & 63;
    int n = gid * 4 + wid;
    const float* xr = x + (size_t)n * DIMD;
    ushort* xbr = xb + (size_t)n * DIMD;
    float acc[NEXP];
#pragma unroll
    for (int e = 0; e < NEXP; e++) acc[e] = 0.f;
    for (int i = 0; i < DIMD / 64; i++) {
        int c = lane + i * 64;
        float xv = xr[c];
        xbr[c] = f2bf(xv);                       // fused conv_x
        const float4* g4 = (const float4*)(gw + (size_t)c * NEXP);
        float4 ga = g4[0], gbv = g4[1];          // vectorized gw (2x float4)
        acc[0] += xv * ga.x;  acc[1] += xv * ga.y;
        acc[2] += xv * ga.z;  acc[3] += xv * ga.w;
        acc[4] += xv * gbv.x; acc[5] += xv * gbv.y;
        acc[6] += xv * gbv.z; acc[7] += xv * gbv.w;
    }
#pragma unroll
    for (int e = 0; e < NEXP; e++) {
        float v = acc[e];
#pragma unroll
        for (int off = 32; off > 0; off >>= 1) v += __shfl_xor(v, off);
        acc[e] = v + gb[e];
    }
    float m = acc[0];
#pragma unroll
    for (int e = 1; e < NEXP; e++) m = fmaxf(m, acc[e]);
    float p[NEXP], s = 0.f;
#pragma unroll
    for (int e = 0; e < NEXP; e++) { p[e] = expf(acc[e] - m); s += p[e]; }
    int e1 = 0;
#pragma unroll
    for (int e = 1; e < NEXP; e++) if (p[e] > p[e1]) e1 = e;
    int e2 = (e1 == 0) ? 1 : 0;
#pragma unroll
    for (int e = 0; e < NEXP; e++) if (e != e1 && p[e] > p[e2]) e2 = e;
    float wa = p[e1] / (p[e1] + p[e2]);
    if (lane == 0) {
        topi[n * 2] = e1; topi[n * 2 + 1] = e2;
        topw[n * 2] = wa; topw[n * 2 + 1] = 1.f - wa;
        atomicAdd(&cs[e1], 1); atomicAdd(&cs[e2], 1);
        float inv = 1.f / s;
#pragma unroll
        for (int e = 0; e < NEXP; e++) atomicAdd(&ps[e], p[e] * inv);
    }
    __syncthreads();
    if (tid < NEXP) { atomicAdd(&probsum[tid], ps[tid]); atomicAdd(&counts[tid], cs[tid]); }
}

// ---------------- routing ----------------
// row_token stores the PAIR index p = token*2 + rank (gemm1 uses p>>1;
// gemm2 stores to pairbuf[p]). Padding slots -> DUMPROW (values discarded).

__global__ void scatter_kernel(const int* __restrict__ topi, const float* __restrict__ topw,
                               const int* __restrict__ counts, int* __restrict__ cursor,
                               int* __restrict__ row_token, float* __restrict__ row_weight) {
    __shared__ int lcnt[NEXP], lbase[NEXP];
    int t = blockIdx.x * 256 + threadIdx.x;       // pair index
    if (threadIdx.x < NEXP) lcnt[threadIdx.x] = 0;
    __syncthreads();
    int e = topi[t];
    int lpos = atomicAdd(&lcnt[e], 1);
    __syncthreads();
    if (threadIdx.x < NEXP) lbase[threadIdx.x] = atomicAdd(&cursor[threadIdx.x], lcnt[threadIdx.x]);
    __syncthreads();
    int pb = 0;
#pragma unroll
    for (int q = 0; q < NEXP; q++) {            // pbase[e] = sum_{q<e} ceil(c_q/128)*128
        int rounded = ((counts[q] + 127) >> 7) << 7;
        pb += (q < e) ? rounded : 0;
    }
    int pos = pb + lbase[e] + lpos;
    row_token[pos] = t;                         // pair index
    row_weight[pos] = topw[t];
}

// ---------------- grouped GEMMs ----------------
// 128x128 tile, BK=64, 4 waves (2x2), mfma_f32_16x16x32_bf16.
// SINGLE 32KB LDS buffer + register-fragment overlap (R9/R10 structure):
//   ds_read ALL frags -> regs ; mid-sync ; issue next tile's global_load_lds
//   into SAME buffer ; sched_barrier ; 32 reg-only MFMAs ; bottom-sync.
// launch_bounds(256,3): 3 blocks/CU, 84 VGPR, NO SPILL. (R11/R16 lesson: any
// occupancy floor pushing below ~84 VGPR -> accumulator spill -> 4x slower.
// R17 lesson: 256-row tiles quantize the ~1024-block grid onto 768-block
// residency -> 1-block/CU tail round; 128^2 stays.)
// LDS XOR-swizzle (byte ^= (row&7)<<4) on BOTH staging source and read.
// Block -> work via closed-form slot_map (XCD-affine; s%8 == expert).
// gemm1 carries TW2 TAIL blocks (blockIdx >= G1) doing the w2 transpose.

__global__ __launch_bounds__(256, 3) void gemm1_kernel(
        const ushort* __restrict__ xb, const ushort* __restrict__ w1t,
        const float* __restrict__ b1, ushort* __restrict__ hbuf,
        const int* __restrict__ row_token, const int* __restrict__ counts,
        const float* __restrict__ w2, ushort* __restrict__ w2t) {
    __shared__ alignas(16) char smem[SMEM_BYTES];
    ushort* ldsA = (ushort*)smem;
    ushort* ldsB = (ushort*)(smem + 16384);
    int tid = threadIdx.x;
    if (blockIdx.x >= G1) {
        int id = blockIdx.x - G1;                // w2: R=HDIM, C=DIMD; 32x8=256 tiles/e
        int e = id >> 8, tt = id & 255;
        int rt = tt >> 3, ct = tt & 7;
        transpose_tile(w2 + (size_t)e * HDIM * DIMD, w2t + (size_t)e * HDIM * DIMD,
                       HDIM, DIMD, rt, ct, (float(*)[129])smem, tid);
        return;
    }
    int e, tm, nb;
    if (!slot_map(counts, blockIdx.x, 16, CAP1, &e, &tm, &nb)) return;
    int nbase = nb * BN;
    int slotbase = tm * BM;
    int lane = tid & 63, wid = tid >> 6;
    int wr = wid >> 1, wc = wid & 1;
    f32x4 acc[4][4];
#pragma unroll
    for (int i = 0; i < 4; i++)
#pragma unroll
        for (int j = 0; j < 4; j++) acc[i][j] = (f32x4){0.f, 0.f, 0.f, 0.f};
    int arow[4], acol[4], tok[4];
#pragma unroll
    for (int i = 0; i < 4; i++) {
        int p = i * 4096 + wid * 1024 + lane * 16;   // linear LDS byte offset
        int row = p >> 7;
        int srclo = (p & 127) ^ ((row & 7) << 4);    // inverse-swizzled source column
        arow[i] = row; acol[i] = srclo >> 1;
        tok[i] = row_token[slotbase + row] >> 1;     // pair -> token
    }
    const ushort* bmat = w1t + (size_t)e * HDIM * DIMD;
    const int NT = DIMD / BKK;

    // prologue: stage tile 0
#pragma unroll
    for (int i = 0; i < 4; i++) {
        gload_lds16(xb + (size_t)tok[i] * DIMD + acol[i], ldsA + i * 2048 + wid * 512);
        gload_lds16(bmat + (size_t)(nbase + arow[i]) * DIMD + acol[i],
                    ldsB + i * 2048 + wid * 512);
    }
    __syncthreads();

    for (int kt = 0; kt < NT; kt++) {
        short8 af[4][2], bfv[4][2];
#pragma unroll
        for (int kk = 0; kk < 2; kk++) {
#pragma unroll
            for (int im = 0; im < 4; im++) {
                int row = wr * 64 + im * 16 + (lane & 15);
                int kbyte = kk * 64 + ((lane >> 4) * 16);
                af[im][kk] = *(const short8*)((const char*)ldsA +
                              row * 128 + (kbyte ^ ((row & 7) << 4)));
            }
#pragma unroll
            for (int in = 0; in < 4; in++) {
                int row = wc * 64 + in * 16 + (lane & 15);
                int kbyte = kk * 64 + ((lane >> 4) * 16);
                bfv[in][kk] = *(const short8*)((const char*)ldsB +
                               row * 128 + (kbyte ^ ((row & 7) << 4)));
            }
        }
        __syncthreads();                           // all reads done -> buffer reusable
        if (kt + 1 < NT) {
            int k0 = (kt + 1) * BKK;
#pragma unroll
            for (int i = 0; i < 4; i++) {
                gload_lds16(xb + (size_t)tok[i] * DIMD + k0 + acol[i],
                            ldsA + i * 2048 + wid * 512);
                gload_lds16(bmat + (size_t)(nbase + arow[i]) * DIMD + k0 + acol[i],
                            ldsB + i * 2048 + wid * 512);
            }
        }
        __builtin_amdgcn_sched_barrier(0);         // pin load-issue before MFMAs
#pragma unroll
        for (int kk = 0; kk < 2; kk++)
#pragma unroll
            for (int im = 0; im < 4; im++)
#pragma unroll
                for (int in = 0; in < 4; in++)
                    acc[im][in] = __builtin_amdgcn_mfma_f32_16x16x32_bf16(
                        af[im][kk], bfv[in][kk], acc[im][in], 0, 0, 0);
        __syncthreads();                           // drains vmcnt(0): next tile ready
    }
    const float* b1e = b1 + (size_t)e * HDIM;
#pragma unroll
    for (int im = 0; im < 4; im++) {
#pragma unroll
        for (int in = 0; in < 4; in++) {
            int col = nbase + wc * 64 + in * 16 + (lane & 15);
            float bias = b1e[col];
#pragma unroll
            for (int r = 0; r < 4; r++) {
                int row = slotbase + wr * 64 + im * 16 + (lane >> 4) * 4 + r;
                float v = fmaxf(acc[im][in][r] + bias, 0.f);
                hbuf[(size_t)row * HDIM + col] = f2bf(v);
            }
        }
    }
}

__global__ __launch_bounds__(256, 3) void gemm2_kernel(
        const ushort* __restrict__ hbuf, const ushort* __restrict__ w2t,
        const float* __restrict__ b2, __half* __restrict__ pairbuf,
        const int* __restrict__ row_token, const float* __restrict__ row_weight,
        const int* __restrict__ counts) {
    int e, tm, nb;
    if (!slot_map(counts, blockIdx.x, 8, CAP2, &e, &tm, &nb)) return;
    int nbase = nb * BN;
    int slotbase = tm * BM;
    __shared__ alignas(16) ushort ldsA[BM * BKK];
    __shared__ alignas(16) ushort ldsB[BN * BKK];
    int tid = threadIdx.x, lane = tid & 63, wid = tid >> 6;
    int wr = wid >> 1, wc = wid & 1;
    f32x4 acc[4][4];
#pragma unroll
    for (int i = 0; i < 4; i++)
#pragma unroll
        for (int j = 0; j < 4; j++) acc[i][j] = (f32x4){0.f, 0.f, 0.f, 0.f};
    int arow[4], acol[4];
#pragma unroll
    for (int i = 0; i < 4; i++) {
        int p = i * 4096 + wid * 1024 + lane * 16;
        int row = p >> 7;
        int srclo = (p & 127) ^ ((row & 7) << 4);
        arow[i] = row; acol[i] = srclo >> 1;
    }
    const ushort* amat = hbuf + (size_t)slotbase * HDIM;
    const ushort* bmat = w2t + (size_t)e * DIMD * HDIM;
    const int NT = HDIM / BKK;

#pragma unroll
    for (int i = 0; i < 4; i++) {
        gload_lds16(amat + (size_t)arow[i] * HDIM + acol[i], &ldsA[i * 2048 + wid * 512]);
        gload_lds16(bmat + (size_t)(nbase + arow[i]) * HDIM + acol[i],
                    &ldsB[i * 2048 + wid * 512]);
    }
    __syncthreads();

    for (int kt = 0; kt < NT; kt++) {
        short8 af[4][2], bfv[4][2];
#pragma unroll
        for (int kk = 0; kk < 2; kk++) {
#pragma unroll
            for (int im = 0; im < 4; im++) {
                int row = wr * 64 + im * 16 + (lane & 15);
                int kbyte = kk * 64 + ((lane >> 4) * 16);
                af[im][kk] = *(const short8*)((const char*)ldsA +
                              row * 128 + (kbyte ^ ((row & 7) << 4)));
            }
#pragma unroll
            for (int in = 0; in < 4; in++) {
                int row = wc * 64 + in * 16 + (lane & 15);
                int kbyte = kk * 64 + ((lane >> 4) * 16);
                bfv[in][kk] = *(const short8*)((const char*)ldsB +
                               row * 128 + (kbyte ^ ((row & 7) << 4)));
            }
        }
        __syncthreads();
        if (kt + 1 < NT) {
            int k0 = (kt + 1) * BKK;
#pragma unroll
            for (int i = 0; i < 4; i++) {
                gload_lds16(amat + (size_t)arow[i] * HDIM + k0 + acol[i],
                            &ldsA[i * 2048 + wid * 512]);
                gload_lds16(bmat + (size_t)(nbase + arow[i]) * HDIM + k0 + acol[i],
                            &ldsB[i * 2048 + wid * 512]);
            }
        }
        __builtin_amdgcn_sched_barrier(0);
#pragma unroll
        for (int kk = 0; kk < 2; kk++)
#pragma unroll
            for (int im = 0; im < 4; im++)
#pragma unroll
                for (int in = 0; in < 4; in++)
                    acc[im][in] = __builtin_amdgcn_mfma_f32_16x16x32_bf16(
                        af[im][kk], bfv[in][kk], acc[im][in], 0, 0, 0);
        __syncthreads();
    }
    const float* b2e = b2 + (size_t)e * DIMD;
#pragma unroll
    for (int im = 0; im < 4; im++) {
#pragma unroll
        for (int r = 0; r < 4; r++) {
            int srow = slotbase + wr * 64 + im * 16 + (lane >> 4) * 4 + r;
            int pair = row_token[srow];
            float w = row_weight[srow];
            __half* prow = pairbuf + (size_t)pair * DIMD;
#pragma unroll
            for (int in = 0; in < 4; in++) {
                int col = nbase + wc * 64 + in * 16 + (lane & 15);
                float v = acc[im][in][r] + b2e[col];
                prow[col] = __float2half(w * v);     // plain store, no atomic
            }
        }
    }
}

// out[t][d] = pairbuf[2t][d] + pairbuf[2t+1][d]  (short8 loads, 8 elems/thread)
// + fused loss finalize on thread 0 of block 0.
__global__ void combine_kernel(const __half* __restrict__ pairbuf, float* __restrict__ outp,
                               const float* __restrict__ probsum, const int* __restrict__ counts) {
    int i = blockIdx.x * blockDim.x + threadIdx.x;
    int o = i * 8;                       // 8 consecutive d within one token row
    int t = o >> 10, d = o & 1023;
    const __half* p0 = pairbuf + ((size_t)(t * 2) << 10) + d;
    const __half* p1 = p0 + DIMD;
    short8 h0 = *(const short8*)p0;
    short8 h1 = *(const short8*)p1;
    float4 r0, r1;
#pragma unroll
    for (int j = 0; j < 4; j++) {
        ((float*)&r0)[j] = __half2float(__ushort_as_half((ushort)h0[j])) +
                           __half2float(__ushort_as_half((ushort)h1[j]));
        ((float*)&r1)[j] = __half2float(__ushort_as_half((ushort)h0[j + 4])) +
                           __half2float(__ushort_as_half((ushort)h1[j + 4]));
    }
    float4* dst = (float4*)(outp + o);
    dst[0] = r0; dst[1] = r1;
    if (i == 0) {
        float l = 0.f;
#pragma unroll
        for (int e = 0; e < NEXP; e++) l += probsum[e] * (float)counts[e];
        outp[(size_t)N_TOK * DIMD] = l / ((float)N_TOK * (float)N_TOK);
    }
}

// ---------------- launch ----------------

extern "C" void kernel_launch(void* const* d_in, const int* in_sizes, int n_in,
                              void* d_out, int out_size, void* d_ws, size_t ws_size,
                              hipStream_t stream) {
    const float* x      = (const float*)d_in[0];
    const float* gate_w = (const float*)d_in[1];
    const float* gate_b = (const float*)d_in[2];
    const float* w1     = (const float*)d_in[3];
    const float* b1     = (const float*)d_in[4];
    const float* w2     = (const float*)d_in[5];
    const float* b2     = (const float*)d_in[6];
    float* outp = (float*)d_out;

    char* ws = (char*)d_ws;
    ushort* xb   = (ushort*)(ws);                 // 16.8 MB   [dead after gemm1]
    ushort* w1t  = (ushort*)(ws + 16777216);      // 33.6 MB   [dead after gemm1]
    ushort* w2t  = (ushort*)(ws + 50331648);      // 33.6 MB  [E][D][H] bf16
    ushort* hbuf = (ushort*)(ws + 83886080);      // 71.3 MB  [MAXROWS][H] bf16
    __half* pairbuf = (__half*)(ws);              // 33.6 MB  [2N+1][D] f16 (overlays xb/w1t)
    char* ctrl   = ws + 155189248;
    int*   counts     = (int*)(ctrl + 0);
    int*   cursor     = (int*)(ctrl + 32);
    float* probsum    = (float*)(ctrl + 64);
    int*   topi       = (int*)(ctrl + 2048);
    float* topw       = (float*)(ctrl + 2048 + 65536);
    int*   row_token  = (int*)(ctrl + 2048 + 131072);
    float* row_weight = (float*)(ctrl + 2048 + 131072 + 69632);

    hipMemsetAsync(ctrl, 0, 128, stream);

    prep_kernel<<<TRB1 + N_TOK / 4, 256, 0, stream>>>(w1, w1t, x, gate_w, gate_b,
                                                      topi, topw, counts, probsum, xb,
                                                      row_token, row_weight);
    scatter_kernel<<<(N_TOK * 2) / 256, 256, 0, stream>>>(topi, topw, counts, cursor,
                                                          row_token, row_weight);
    gemm1_kernel<<<G1 + TW2, 256, 0, stream>>>(xb, w1t, b1, hbuf, row_token, counts,
                                               w2, w2t);
    gemm2_kernel<<<G2, 256, 0, stream>>>(hbuf, w2t, b2, pairbuf, row_token, row_weight, counts);
    combine_kernel<<<(N_TOK * DIMD / 8) / 256, 256, 0, stream>>>(pairbuf, outp,
                                                                 probsum, counts);
}